// Round 8
// baseline (165.958 us; speedup 1.0000x reference)
//
#include <hip/hip_runtime.h>
#include <hip/hip_bf16.h>

typedef short v8s __attribute__((ext_vector_type(8)));
typedef float v4f __attribute__((ext_vector_type(4)));

#define THREADS 256
#define ROWS_PER_WAVE 64     // 4 M-tiles of 16; block = 4 waves = 256 rows
#define BMROWS  256
// uint4 bases of fragment-ready weight tables in d_ws
#define W1F_U4  0       // 49 frags * 64 uint4
#define W2F_U4  3136    // 28 frags
#define W3F_U4  4928    // 16 frags

__device__ __forceinline__ unsigned short f2bf(float f) {
    union { __hip_bfloat16 h; unsigned short u; } c;
    c.h = __float2bfloat16(f);
    return c.u;
}
__device__ __forceinline__ unsigned pk2(float a, float b) {
    return (unsigned)f2bf(a) | ((unsigned)f2bf(b) << 16);
}
__device__ __forceinline__ v4f mfma16(v8s a, v8s b, v4f c) {
    return __builtin_amdgcn_mfma_f32_16x16x32_bf16(a, b, c, 0, 0, 0);
}
__device__ __forceinline__ v8s mkfrag(float4 a, float4 b) {
    union { unsigned u[4]; v8s s; } t;
    t.u[0] = pk2(a.x, a.y); t.u[1] = pk2(a.z, a.w);
    t.u[2] = pk2(b.x, b.y); t.u[3] = pk2(b.z, b.w);
    return t.s;
}

// ---- prep: weights -> MFMA B-fragment layout (bf16, zero-padded) ----------
// frag(nt,kc): lane l holds B[k = kc*32+(l>>4)*8+j][n = nt*16+(l&15)], j=0..7
__global__ void prep_weights(const float* __restrict__ W1,
                             const float* __restrict__ W2,
                             const float* __restrict__ W3,
                             uint4* __restrict__ wf) {
    const int bid = blockIdx.x, l = threadIdx.x;
    const float* W; int K, N, KC, base, f;
    if (bid < 49)      { W = W1; K = 200; N = 100; KC = 7; base = W1F_U4; f = bid; }
    else if (bid < 77) { W = W2; K = 100; N = 100; KC = 4; base = W2F_U4; f = bid - 49; }
    else               { W = W3; K = 100; N = 64;  KC = 4; base = W3F_U4; f = bid - 77; }
    const int kc = f % KC;
    const int n  = (f / KC) * 16 + (l & 15);
    unsigned u[4];
    #pragma unroll
    for (int p = 0; p < 4; ++p) {
        const int k0 = kc * 32 + (l >> 4) * 8 + p * 2;
        const float a = (k0     < K && n < N) ? W[(size_t)k0 * N + n]       : 0.f;
        const float b = (k0 + 1 < K && n < N) ? W[(size_t)(k0 + 1) * N + n] : 0.f;
        u[p] = pk2(a, b);
    }
    wf[base + f * 64 + l] = make_uint4(u[0], u[1], u[2], u[3]);
}

// Per-wave 16 KiB slab: [64 rows][256 B], XOR-16 granule swizzle.
// Reused h1(bf16[64][128]) -> h2 -> DP(f32[64][64]) via in-wave DS ordering.
__device__ __forceinline__ int sladdr(int wid, int row, int byte) {
    return (wid << 14) + (row << 8) + ((((byte >> 4) ^ row) & 15) << 4) + (byte & 15);
}

__global__ __launch_bounds__(THREADS, 2)   // 256-reg cap incl AGPR; ~240 live
void ar_gas_v7(const float* __restrict__ x,
               const float* __restrict__ last_mu,
               const float* __restrict__ last_sigma,
               const float* __restrict__ p_amu, const float* __restrict__ p_as,
               const float* __restrict__ p_bmu, const float* __restrict__ p_bs,
               const float* __restrict__ p_omu, const float* __restrict__ p_os,
               const float* __restrict__ p_nu,  const float* __restrict__ p_ns,
               const float* __restrict__ b1, const float* __restrict__ b2,
               const float* __restrict__ b3,
               const uint4* __restrict__ wf,
               float* __restrict__ out)
{
    __shared__ __align__(16) unsigned char L[65536];
    const int tid  = threadIdx.x;
    const int lane = tid & 63;
    const int wid  = tid >> 6;
    const int l15  = lane & 15;
    const int l4   = lane >> 4;
    const int blk  = blockIdx.x;

    // wave-private global rows [gw, gw+64); mt sub-tile rows gw+mt*16+l15
    const size_t gw = (size_t)blk * BMROWS + (size_t)wid * ROWS_PER_WAVE;
    const float* xr = x + (gw + l15) * 200;   // + mt*3200 floats per M-tile

    // X chunk load: 8 floats at k = kc*32 + l4*8 for row-tile mt.
    // kc=6 covers k=192..224; only l4==0 is in-bounds (192..200); clamp the
    // rest to a valid addr — garbage lanes hit zero-padded W1 frags (k>=200).
#define XLOAD(d0, d1, mt, kk)                                           \
    { int kb = (kk) * 32 + l4 * 8;                                      \
      if ((kk) == 6) kb = (l4 == 0) ? 192 : 168;                        \
      d0 = *(const float4*)(xr + (mt) * 3200 + kb);                     \
      d1 = *(const float4*)(xr + (mt) * 3200 + kb + 4); }

    // ================= layer 1: h1 = relu(X @ W1 + b1) =================
    v4f acc[4][7];                             // 112 accumulator regs
    #pragma unroll
    for (int mt = 0; mt < 4; ++mt)
        #pragma unroll
        for (int nt = 0; nt < 7; ++nt) acc[mt][nt] = (v4f){0.f, 0.f, 0.f, 0.f};

    uint4 bu[2][7];                            // frag double-buffer (56 regs)
    #pragma unroll
    for (int nt = 0; nt < 7; ++nt)
        bu[0][nt] = wf[W1F_U4 + (nt * 7 + 0) * 64 + lane];

    float4 xv[4][2];                           // current X chunk (32 regs)
    #pragma unroll
    for (int mt = 0; mt < 4; ++mt) XLOAD(xv[mt][0], xv[mt][1], mt, 0);

    #pragma unroll
    for (int kc = 0; kc < 7; ++kc) {
        if (kc < 6) {                          // frags one kc ahead
            #pragma unroll
            for (int nt = 0; nt < 7; ++nt)
                bu[(kc + 1) & 1][nt] = wf[W1F_U4 + (nt * 7 + kc + 1) * 64 + lane];
        }
        v8s af[4];
        #pragma unroll
        for (int mt = 0; mt < 4; ++mt) af[mt] = mkfrag(xv[mt][0], xv[mt][1]);
        if (kc < 6) {                          // refill X (single-buffered)
            #pragma unroll
            for (int mt = 0; mt < 4; ++mt) XLOAD(xv[mt][0], xv[mt][1], mt, kc + 1);
        }
        #pragma unroll
        for (int nt = 0; nt < 7; ++nt) {
            const v8s bf = *(const v8s*)&bu[kc & 1][nt];
            #pragma unroll
            for (int mt = 0; mt < 4; ++mt)
                acc[mt][nt] = mfma16(af[mt], bf, acc[mt][nt]);
        }
    }
#undef XLOAD

    // epilogue -> slab (bf16), wave-private
    {
        float bv[7];
        #pragma unroll
        for (int nt = 0; nt < 7; ++nt) {
            const int c = nt * 16 + l15;
            bv[nt] = (c < 100) ? b1[c] : 0.f;
        }
        #pragma unroll
        for (int mt = 0; mt < 4; ++mt)
            #pragma unroll
            for (int nt = 0; nt < 7; ++nt) {
                #pragma unroll
                for (int r = 0; r < 4; ++r) {
                    const int row = mt * 16 + l4 * 4 + r;   // slab-local 0..63
                    const int c   = nt * 16 + l15;
                    const float v = fmaxf(acc[mt][nt][r] + bv[nt], 0.f);
                    *(unsigned short*)(&L[sladdr(wid, row, c * 2)]) = f2bf(v);
                }
            }
    }
    // zero cols 112..127 for all 64 rows (100..111 zero via padded W1 frags)
    *(uint4*)(&L[sladdr(wid, lane, 224)]) = make_uint4(0, 0, 0, 0);
    *(uint4*)(&L[sladdr(wid, lane, 240)]) = make_uint4(0, 0, 0, 0);

    // ================= layer 2: h2 = relu(h1 @ W2 + b2) =================
    v4f acc2[4][7];
    #pragma unroll
    for (int mt = 0; mt < 4; ++mt)
        #pragma unroll
        for (int nt = 0; nt < 7; ++nt) acc2[mt][nt] = (v4f){0.f, 0.f, 0.f, 0.f};

    #pragma unroll
    for (int nt = 0; nt < 7; ++nt)
        bu[0][nt] = wf[W2F_U4 + (nt * 4 + 0) * 64 + lane];

    #pragma unroll
    for (int kc = 0; kc < 4; ++kc) {
        if (kc < 3) {
            #pragma unroll
            for (int nt = 0; nt < 7; ++nt)
                bu[(kc + 1) & 1][nt] = wf[W2F_U4 + (nt * 4 + kc + 1) * 64 + lane];
        }
        uint4 t[4];
        #pragma unroll
        for (int mt = 0; mt < 4; ++mt)
            t[mt] = *(const uint4*)(&L[sladdr(wid, mt * 16 + l15, kc * 64 + l4 * 16)]);
        #pragma unroll
        for (int nt = 0; nt < 7; ++nt) {
            const v8s bf = *(const v8s*)&bu[kc & 1][nt];
            #pragma unroll
            for (int mt = 0; mt < 4; ++mt)
                acc2[mt][nt] = mfma16(*(const v8s*)&t[mt], bf, acc2[mt][nt]);
        }
    }
    {
        float bv2[7];
        #pragma unroll
        for (int nt = 0; nt < 7; ++nt) {
            const int c = nt * 16 + l15;
            bv2[nt] = (c < 100) ? b2[c] : 0.f;
        }
        // h2 overwrites h1 in-place (in-wave DS ordering); pad cols keep zeros
        #pragma unroll
        for (int mt = 0; mt < 4; ++mt)
            #pragma unroll
            for (int nt = 0; nt < 7; ++nt) {
                #pragma unroll
                for (int r = 0; r < 4; ++r) {
                    const int row = mt * 16 + l4 * 4 + r;
                    const int c   = nt * 16 + l15;
                    const float v = fmaxf(acc2[mt][nt][r] + bv2[nt], 0.f);
                    *(unsigned short*)(&L[sladdr(wid, row, c * 2)]) = f2bf(v);
                }
            }
    }

    // ================= layer 3: DP = h2 @ W3 + b3 =================
    v4f acc3[4][4];
    #pragma unroll
    for (int mt = 0; mt < 4; ++mt)
        #pragma unroll
        for (int nt = 0; nt < 4; ++nt) acc3[mt][nt] = (v4f){0.f, 0.f, 0.f, 0.f};

    #pragma unroll
    for (int nt = 0; nt < 4; ++nt)
        bu[0][nt] = wf[W3F_U4 + (nt * 4 + 0) * 64 + lane];

    #pragma unroll
    for (int kc = 0; kc < 4; ++kc) {
        if (kc < 3) {
            #pragma unroll
            for (int nt = 0; nt < 4; ++nt)
                bu[(kc + 1) & 1][nt] = wf[W3F_U4 + (nt * 4 + kc + 1) * 64 + lane];
        }
        uint4 t[4];
        #pragma unroll
        for (int mt = 0; mt < 4; ++mt)
            t[mt] = *(const uint4*)(&L[sladdr(wid, mt * 16 + l15, kc * 64 + l4 * 16)]);
        #pragma unroll
        for (int nt = 0; nt < 4; ++nt) {
            const v8s bf = *(const v8s*)&bu[kc & 1][nt];
            #pragma unroll
            for (int mt = 0; mt < 4; ++mt)
                acc3[mt][nt] = mfma16(*(const v8s*)&t[mt], bf, acc3[mt][nt]);
        }
    }
    {
        float bv3[4];
        #pragma unroll
        for (int nt = 0; nt < 4; ++nt) bv3[nt] = b3[nt * 16 + l15];
        // DP (f32 [64 rows][64]) overwrites slab (h2 reads precede)
        #pragma unroll
        for (int mt = 0; mt < 4; ++mt)
            #pragma unroll
            for (int nt = 0; nt < 4; ++nt) {
                #pragma unroll
                for (int r = 0; r < 4; ++r) {
                    const int row = mt * 16 + l4 * 4 + r;
                    const int c   = nt * 16 + l15;
                    *(float*)(&L[sladdr(wid, row, c * 4)]) = acc3[mt][nt][r] + bv3[nt];
                }
            }
    }

    // ====== Student-t GAS recurrence: ALL 64 lanes, row = lane ======
    {
        const size_t rg = gw + lane;
        float mu = last_mu[rg];
        float s2 = last_sigma[rg];
        const float anu = *p_nu,  ans = *p_ns;
        const float aMu = *p_amu, aSg = *p_as;
        const float bMu = *p_bmu, bSg = *p_bs;
        const float oMu = *p_omu, oSg = *p_os;
        const float w   = 1.f + __builtin_amdgcn_rcpf(anu);
        const float cmu = ans * aMu * w;
        const float cs  = ans * aSg * w;
        const float bs2 = bSg - ans * aSg;

#define GAS_STEP(Y, O)                                                  \
        {   const float e    = (Y) - mu;                                \
            const float nus2 = anu * s2;                                \
            const float den  = fmaf(e, e, nus2);                        \
            const float r0   = __builtin_amdgcn_rcpf(den);              \
            const float p    = e * nus2 * r0;                           \
            mu = fmaf(cmu, p, fmaf(bMu, mu, oMu));                      \
            s2 = fmaf(cs, e * p, fmaf(bs2, s2, oSg));                   \
            (O) = fmaf((Y), __builtin_amdgcn_sqrtf(s2), mu); }

        #pragma unroll
        for (int q = 0; q < 16; ++q) {
            float4 d = *(float4*)(&L[sladdr(wid, lane, q * 16)]);
            float o0, o1, o2, o3;
            GAS_STEP(d.x, o0); GAS_STEP(d.y, o1);
            GAS_STEP(d.z, o2); GAS_STEP(d.w, o3);
            *(float4*)(&L[sladdr(wid, lane, q * 16)]) = make_float4(o0, o1, o2, o3);
        }
#undef GAS_STEP
    }

    // ============ wave-wide coalesced float4 store (no barrier) ============
    #pragma unroll
    for (int i = 0; i < 16; ++i) {
        const int fi  = i * 64 + lane;           // 1024 float4 = 64 rows x 16
        const int row = fi >> 4, q = fi & 15;
        float4 v = *(float4*)(&L[sladdr(wid, row, q * 16)]);
        ((float4*)out)[gw * 16 + fi] = v;
    }
}

extern "C" void kernel_launch(void* const* d_in, const int* in_sizes, int n_in,
                              void* d_out, int out_size, void* d_ws, size_t ws_size,
                              hipStream_t stream) {
    const float* x          = (const float*)d_in[0];
    const float* last_mu    = (const float*)d_in[1];
    const float* last_sigma = (const float*)d_in[2];
    const float* amu        = (const float*)d_in[3];
    const float* asig       = (const float*)d_in[4];
    const float* bmu        = (const float*)d_in[5];
    const float* bsig       = (const float*)d_in[6];
    const float* omu        = (const float*)d_in[7];
    const float* osig       = (const float*)d_in[8];
    const float* nu         = (const float*)d_in[9];
    const float* ns         = (const float*)d_in[10];
    const float* W1         = (const float*)d_in[11];
    const float* b1         = (const float*)d_in[12];
    const float* W2         = (const float*)d_in[13];
    const float* b2         = (const float*)d_in[14];
    const float* W3         = (const float*)d_in[15];
    const float* b3         = (const float*)d_in[16];
    float* out = (float*)d_out;

    uint4* wf = (uint4*)d_ws;   // 95,232 B of fragment-ready bf16 weights
    prep_weights<<<93, 64, 0, stream>>>(W1, W2, W3, wf);

    const int B = in_sizes[1];                 // 262144
    dim3 grid(B / BMROWS), block(THREADS);     // 1024 blocks
    ar_gas_v7<<<grid, block, 0, stream>>>(
        x, last_mu, last_sigma,
        amu, asig, bmu, bsig, omu, osig, nu, ns,
        b1, b2, b3, wf, out);
}

// Round 9
// 104.632 us; speedup vs baseline: 1.5861x; 1.5861x over previous
//
#include <hip/hip_runtime.h>
#include <hip/hip_bf16.h>

typedef short v8s __attribute__((ext_vector_type(8)));
typedef float v4f __attribute__((ext_vector_type(4)));

#define THREADS 256
#define BMROWS  128     // 32 rows per wave (2 M-tiles of 16)
// uint4 bases of fragment-ready weight tables in d_ws
#define W1F_U4  0       // 49 frags * 64 uint4
#define W2F_U4  3136    // 28 frags
#define W3F_U4  4928    // 16 frags

__device__ __forceinline__ unsigned short f2bf(float f) {
    union { __hip_bfloat16 h; unsigned short u; } c;
    c.h = __float2bfloat16(f);
    return c.u;
}
__device__ __forceinline__ unsigned pk2(float a, float b) {
    return (unsigned)f2bf(a) | ((unsigned)f2bf(b) << 16);
}
__device__ __forceinline__ v4f mfma16(v8s a, v8s b, v4f c) {
    return __builtin_amdgcn_mfma_f32_16x16x32_bf16(a, b, c, 0, 0, 0);
}
__device__ __forceinline__ v8s mkfrag(float4 a, float4 b) {
    union { unsigned u[4]; v8s s; } t;
    t.u[0] = pk2(a.x, a.y); t.u[1] = pk2(a.z, a.w);
    t.u[2] = pk2(b.x, b.y); t.u[3] = pk2(b.z, b.w);
    return t.s;
}

// ---- prep: weights -> MFMA B-fragment layout (bf16, zero-padded) ----------
// frag(nt,kc): lane l holds B[k = kc*32+(l>>4)*8+j][n = nt*16+(l&15)], j=0..7
__global__ void prep_weights(const float* __restrict__ W1,
                             const float* __restrict__ W2,
                             const float* __restrict__ W3,
                             uint4* __restrict__ wf) {
    const int bid = blockIdx.x, l = threadIdx.x;
    const float* W; int K, N, KC, base, f;
    if (bid < 49)      { W = W1; K = 200; N = 100; KC = 7; base = W1F_U4; f = bid; }
    else if (bid < 77) { W = W2; K = 100; N = 100; KC = 4; base = W2F_U4; f = bid - 49; }
    else               { W = W3; K = 100; N = 64;  KC = 4; base = W3F_U4; f = bid - 77; }
    const int kc = f % KC;
    const int n  = (f / KC) * 16 + (l & 15);
    unsigned u[4];
    #pragma unroll
    for (int p = 0; p < 4; ++p) {
        const int k0 = kc * 32 + (l >> 4) * 8 + p * 2;
        const float a = (k0     < K && n < N) ? W[(size_t)k0 * N + n]       : 0.f;
        const float b = (k0 + 1 < K && n < N) ? W[(size_t)(k0 + 1) * N + n] : 0.f;
        u[p] = pk2(a, b);
    }
    wf[base + f * 64 + l] = make_uint4(u[0], u[1], u[2], u[3]);
}

// Per-wave 8 KiB slab: [32 rows][256 B], XOR-16 granule swizzle.
// Reused h1(bf16[32][128]) -> h2 -> DP(f32[32][64]) via in-wave DS ordering.
__device__ __forceinline__ int sladdr(int wid, int row, int byte) {
    return (wid << 13) + (row << 8) + ((((byte >> 4) ^ row) & 15) << 4) + (byte & 15);
}

__global__ __launch_bounds__(THREADS, 2)   // 256-reg cap incl AGPR; ~185 live
void ar_gas_v8(const float* __restrict__ x,
               const float* __restrict__ last_mu,
               const float* __restrict__ last_sigma,
               const float* __restrict__ p_amu, const float* __restrict__ p_as,
               const float* __restrict__ p_bmu, const float* __restrict__ p_bs,
               const float* __restrict__ p_omu, const float* __restrict__ p_os,
               const float* __restrict__ p_nu,  const float* __restrict__ p_ns,
               const float* __restrict__ b1, const float* __restrict__ b2,
               const float* __restrict__ b3,
               const uint4* __restrict__ wf,
               float* __restrict__ out)
{
    __shared__ __align__(16) unsigned char L[32768];
    const int tid  = threadIdx.x;
    const int lane = tid & 63;
    const int wid  = tid >> 6;
    const int l15  = lane & 15;
    const int l4   = lane >> 4;
    const int blk  = blockIdx.x;

    // wave-private global rows [gw, gw+32)
    const size_t gw = (size_t)blk * BMROWS + (size_t)wid * 32;
    const float* xp0 = x + (gw + l15) * 200;        // mt=0 A-rows
    const float* xp1 = x + (gw + 16 + l15) * 200;   // mt=1 A-rows

    // Unconditional 32B loads; tail lanes clamp to a valid addr — their
    // garbage values hit zero-padded W1 frag rows (k>=200) so contribute 0.
#define XLOAD(d0, d1, xp, kk)                                           \
    { int kb = (kk) * 32 + l4 * 8;                                      \
      kb = (kb + 8 <= 200) ? kb : 168;                                  \
      d0 = *(const float4*)((xp) + kb);                                 \
      d1 = *(const float4*)((xp) + kb + 4); }

    // ================= layer 1: h1 = relu(X @ W1 + b1) =================
    v4f acc[2][7];                          // 56 accumulator regs
    #pragma unroll
    for (int mt = 0; mt < 2; ++mt)
        #pragma unroll
        for (int nt = 0; nt < 7; ++nt) acc[mt][nt] = (v4f){0.f, 0.f, 0.f, 0.f};
    float bv[7];
    #pragma unroll
    for (int nt = 0; nt < 7; ++nt) {
        const int c = nt * 16 + l15;
        bv[nt] = (c < 100) ? b1[c] : 0.f;
    }

    uint4 bu[2][7];                         // frag double-buffer (56 regs)
    #pragma unroll
    for (int nt = 0; nt < 7; ++nt)
        bu[0][nt] = wf[W1F_U4 + (nt * 7 + 0) * 64 + lane];

    float4 c0a, c0b, c1a, c1b;
    XLOAD(c0a, c0b, xp0, 0);
    XLOAD(c1a, c1b, xp1, 0);
    #pragma unroll
    for (int kc = 0; kc < 7; ++kc) {
        // prefetch NEXT kc's frags; they land during this kc's 14 MFMAs
        if (kc < 6) {
            #pragma unroll
            for (int nt = 0; nt < 7; ++nt)
                bu[(kc + 1) & 1][nt] = wf[W1F_U4 + (nt * 7 + kc + 1) * 64 + lane];
        }
        const v8s af0 = mkfrag(c0a, c0b);
        const v8s af1 = mkfrag(c1a, c1b);
        if (kc < 6) {                       // prefetch next X chunk
            XLOAD(c0a, c0b, xp0, kc + 1);
            XLOAD(c1a, c1b, xp1, kc + 1);
        }
        #pragma unroll
        for (int nt = 0; nt < 7; ++nt) {
            const v8s bf = *(const v8s*)&bu[kc & 1][nt];
            acc[0][nt] = mfma16(af0, bf, acc[0][nt]);
            acc[1][nt] = mfma16(af1, bf, acc[1][nt]);
        }
    }
#undef XLOAD

    // epilogue -> slab (bf16), wave-private
    #pragma unroll
    for (int mt = 0; mt < 2; ++mt)
        #pragma unroll
        for (int nt = 0; nt < 7; ++nt) {
            #pragma unroll
            for (int r = 0; r < 4; ++r) {
                const int row = mt * 16 + l4 * 4 + r;   // slab-local
                const int c   = nt * 16 + l15;
                const float v = fmaxf(acc[mt][nt][r] + bv[nt], 0.f);
                *(unsigned short*)(&L[sladdr(wid, row, c * 2)]) = f2bf(v);
            }
        }
    // zero cols 112..127 (cols 100..111 are zero via zero-padded W1 frags)
    *(uint4*)(&L[sladdr(wid, lane >> 1, 224 + (lane & 1) * 16)]) =
        make_uint4(0, 0, 0, 0);

    // ================= layer 2: h2 = relu(h1 @ W2 + b2) =================
    v4f acc2[2][7];
    #pragma unroll
    for (int mt = 0; mt < 2; ++mt)
        #pragma unroll
        for (int nt = 0; nt < 7; ++nt) acc2[mt][nt] = (v4f){0.f, 0.f, 0.f, 0.f};
    float bv2[7];
    #pragma unroll
    for (int nt = 0; nt < 7; ++nt) {
        const int c = nt * 16 + l15;
        bv2[nt] = (c < 100) ? b2[c] : 0.f;
    }
    #pragma unroll
    for (int nt = 0; nt < 7; ++nt)
        bu[0][nt] = wf[W2F_U4 + (nt * 4 + 0) * 64 + lane];

    #pragma unroll
    for (int kc = 0; kc < 4; ++kc) {
        if (kc < 3) {                       // frag batch one kc ahead
            #pragma unroll
            for (int nt = 0; nt < 7; ++nt)
                bu[(kc + 1) & 1][nt] = wf[W2F_U4 + (nt * 4 + kc + 1) * 64 + lane];
        }
        uint4 t0 = *(const uint4*)(&L[sladdr(wid, l15,      kc * 64 + l4 * 16)]);
        uint4 t1 = *(const uint4*)(&L[sladdr(wid, 16 + l15, kc * 64 + l4 * 16)]);
        const v8s af0 = *(v8s*)&t0;
        const v8s af1 = *(v8s*)&t1;
        #pragma unroll
        for (int nt = 0; nt < 7; ++nt) {
            const v8s bf = *(const v8s*)&bu[kc & 1][nt];
            acc2[0][nt] = mfma16(af0, bf, acc2[0][nt]);
            acc2[1][nt] = mfma16(af1, bf, acc2[1][nt]);
        }
    }
    // h2 overwrites h1 in-place (in-wave DS ordering); pad cols keep zeros
    #pragma unroll
    for (int mt = 0; mt < 2; ++mt)
        #pragma unroll
        for (int nt = 0; nt < 7; ++nt) {
            #pragma unroll
            for (int r = 0; r < 4; ++r) {
                const int row = mt * 16 + l4 * 4 + r;
                const int c   = nt * 16 + l15;
                const float v = fmaxf(acc2[mt][nt][r] + bv2[nt], 0.f);
                *(unsigned short*)(&L[sladdr(wid, row, c * 2)]) = f2bf(v);
            }
        }

    // ================= layer 3: DP = h2 @ W3 + b3 =================
    v4f acc3[2][4];
    #pragma unroll
    for (int mt = 0; mt < 2; ++mt)
        #pragma unroll
        for (int nt = 0; nt < 4; ++nt) acc3[mt][nt] = (v4f){0.f, 0.f, 0.f, 0.f};
    float bv3[4];
    #pragma unroll
    for (int nt = 0; nt < 4; ++nt) bv3[nt] = b3[nt * 16 + l15];

    #pragma unroll
    for (int nt = 0; nt < 4; ++nt)
        bu[0][nt] = wf[W3F_U4 + (nt * 4 + 0) * 64 + lane];

    #pragma unroll
    for (int kc = 0; kc < 4; ++kc) {
        if (kc < 3) {
            #pragma unroll
            for (int nt = 0; nt < 4; ++nt)
                bu[(kc + 1) & 1][nt] = wf[W3F_U4 + (nt * 4 + kc + 1) * 64 + lane];
        }
        uint4 t0 = *(const uint4*)(&L[sladdr(wid, l15,      kc * 64 + l4 * 16)]);
        uint4 t1 = *(const uint4*)(&L[sladdr(wid, 16 + l15, kc * 64 + l4 * 16)]);
        const v8s af0 = *(v8s*)&t0;
        const v8s af1 = *(v8s*)&t1;
        #pragma unroll
        for (int nt = 0; nt < 4; ++nt) {
            const v8s bf = *(const v8s*)&bu[kc & 1][nt];
            acc3[0][nt] = mfma16(af0, bf, acc3[0][nt]);
            acc3[1][nt] = mfma16(af1, bf, acc3[1][nt]);
        }
    }
    // DP (f32 [32 rows][64]) overwrites slab (h2 reads precede in program order)
    #pragma unroll
    for (int mt = 0; mt < 2; ++mt)
        #pragma unroll
        for (int nt = 0; nt < 4; ++nt) {
            #pragma unroll
            for (int r = 0; r < 4; ++r) {
                const int row = mt * 16 + l4 * 4 + r;
                const int c   = nt * 16 + l15;
                *(float*)(&L[sladdr(wid, row, c * 4)]) = acc3[mt][nt][r] + bv3[nt];
            }
        }

    // ====== Student-t GAS recurrence: per-wave, lane<32 owns one row ======
    if (lane < 32) {
        const size_t rg = gw + lane;
        float mu = last_mu[rg];
        float s2 = last_sigma[rg];
        const float anu = *p_nu,  ans = *p_ns;
        const float aMu = *p_amu, aSg = *p_as;
        const float bMu = *p_bmu, bSg = *p_bs;
        const float oMu = *p_omu, oSg = *p_os;
        const float w   = 1.f + __builtin_amdgcn_rcpf(anu);
        const float cmu = ans * aMu * w;
        const float cs  = ans * aSg * w;
        const float bs2 = bSg - ans * aSg;

#define GAS_STEP(Y, O)                                                  \
        {   const float e    = (Y) - mu;                                \
            const float nus2 = anu * s2;                                \
            const float den  = fmaf(e, e, nus2);                        \
            const float r0   = __builtin_amdgcn_rcpf(den);              \
            const float p    = e * nus2 * r0;                           \
            mu = fmaf(cmu, p, fmaf(bMu, mu, oMu));                      \
            s2 = fmaf(cs, e * p, fmaf(bs2, s2, oSg));                   \
            (O) = fmaf((Y), __builtin_amdgcn_sqrtf(s2), mu); }

        #pragma unroll
        for (int q = 0; q < 16; ++q) {
            float4 d = *(float4*)(&L[sladdr(wid, lane, q * 16)]);
            float o0, o1, o2, o3;
            GAS_STEP(d.x, o0); GAS_STEP(d.y, o1);
            GAS_STEP(d.z, o2); GAS_STEP(d.w, o3);
            *(float4*)(&L[sladdr(wid, lane, q * 16)]) = make_float4(o0, o1, o2, o3);
        }
#undef GAS_STEP
    }

    // ============ wave-wide coalesced float4 store (no barrier) ============
    #pragma unroll
    for (int i = 0; i < 8; ++i) {
        const int fi  = i * 64 + lane;           // 512 float4 = 32 rows x 64
        const int row = fi >> 4, q = fi & 15;
        float4 v = *(float4*)(&L[sladdr(wid, row, q * 16)]);
        ((float4*)out)[gw * 16 + fi] = v;
    }
}

extern "C" void kernel_launch(void* const* d_in, const int* in_sizes, int n_in,
                              void* d_out, int out_size, void* d_ws, size_t ws_size,
                              hipStream_t stream) {
    const float* x          = (const float*)d_in[0];
    const float* last_mu    = (const float*)d_in[1];
    const float* last_sigma = (const float*)d_in[2];
    const float* amu        = (const float*)d_in[3];
    const float* asig       = (const float*)d_in[4];
    const float* bmu        = (const float*)d_in[5];
    const float* bsig       = (const float*)d_in[6];
    const float* omu        = (const float*)d_in[7];
    const float* osig       = (const float*)d_in[8];
    const float* nu         = (const float*)d_in[9];
    const float* ns         = (const float*)d_in[10];
    const float* W1         = (const float*)d_in[11];
    const float* b1         = (const float*)d_in[12];
    const float* W2         = (const float*)d_in[13];
    const float* b2         = (const float*)d_in[14];
    const float* W3         = (const float*)d_in[15];
    const float* b3         = (const float*)d_in[16];
    float* out = (float*)d_out;

    uint4* wf = (uint4*)d_ws;   // 95,232 B of fragment-ready bf16 weights
    prep_weights<<<93, 64, 0, stream>>>(W1, W2, W3, wf);

    const int B = in_sizes[1];                 // 262144
    dim3 grid(B / BMROWS), block(THREADS);
    ar_gas_v8<<<grid, block, 0, stream>>>(
        x, last_mu, last_sigma,
        amu, asig, bmu, bsig, omu, osig, nu, ns,
        b1, b2, b3, wf, out);
}

// Round 10
// 91.610 us; speedup vs baseline: 1.8116x; 1.1422x over previous
//
#include <hip/hip_runtime.h>
#include <hip/hip_bf16.h>

typedef short v8s __attribute__((ext_vector_type(8)));
typedef float v4f __attribute__((ext_vector_type(4)));

#define THREADS 512      // 8 waves
#define WAVES   8
#define BMROWS  256      // 32 rows per wave
#define NFRAGS  96       // 49 (W1) + 28 (W2) + 16 (W3) + 3 pad
#define W1F     0
#define W2F     49
#define W3F     77
#define FRAG_BYTES (NFRAGS * 1024)            // 98304
#define SLAB_BASE  FRAG_BYTES
#define LDS_TOTAL  (FRAG_BYTES + WAVES * 8192) // 163840 = 160 KiB

__device__ __forceinline__ unsigned short f2bf(float f) {
    union { __hip_bfloat16 h; unsigned short u; } c;
    c.h = __float2bfloat16(f);
    return c.u;
}
__device__ __forceinline__ unsigned pk2(float a, float b) {
    return (unsigned)f2bf(a) | ((unsigned)f2bf(b) << 16);
}
__device__ __forceinline__ v4f mfma16(v8s a, v8s b, v4f c) {
    return __builtin_amdgcn_mfma_f32_16x16x32_bf16(a, b, c, 0, 0, 0);
}
__device__ __forceinline__ v8s mkfrag(float4 a, float4 b) {
    union { unsigned u[4]; v8s s; } t;
    t.u[0] = pk2(a.x, a.y); t.u[1] = pk2(a.z, a.w);
    t.u[2] = pk2(b.x, b.y); t.u[3] = pk2(b.z, b.w);
    return t.s;
}
__device__ __forceinline__ void gload_lds16(const void* g, void* l) {
    __builtin_amdgcn_global_load_lds(
        (const __attribute__((address_space(1))) void*)g,
        (__attribute__((address_space(3))) void*)l, 16, 0, 0);
}

// ---- prep: weights -> MFMA B-fragment layout (bf16, zero-padded) ----------
// frag(nt,kc): lane l holds B[k = kc*32+(l>>4)*8+j][n = nt*16+(l&15)], j=0..7
__global__ void prep_weights(const float* __restrict__ W1,
                             const float* __restrict__ W2,
                             const float* __restrict__ W3,
                             uint4* __restrict__ wf) {
    const int bid = blockIdx.x, l = threadIdx.x;
    const float* W; int K, N, KC, base, f;
    if (bid < 49)      { W = W1; K = 200; N = 100; KC = 7; base = W1F * 64; f = bid; }
    else if (bid < 77) { W = W2; K = 100; N = 100; KC = 4; base = W2F * 64; f = bid - 49; }
    else               { W = W3; K = 100; N = 64;  KC = 4; base = W3F * 64; f = bid - 77; }
    const int kc = f % KC;
    const int n  = (f / KC) * 16 + (l & 15);
    unsigned u[4];
    #pragma unroll
    for (int p = 0; p < 4; ++p) {
        const int k0 = kc * 32 + (l >> 4) * 8 + p * 2;
        const float a = (k0     < K && n < N) ? W[(size_t)k0 * N + n]       : 0.f;
        const float b = (k0 + 1 < K && n < N) ? W[(size_t)(k0 + 1) * N + n] : 0.f;
        u[p] = pk2(a, b);
    }
    wf[base + f * 64 + l] = make_uint4(u[0], u[1], u[2], u[3]);
}

// Per-wave 8 KiB slab above the frag region: [32 rows][256 B], XOR-16 swizzle.
// Reused h1(bf16) -> h2 -> DP(f32) via in-wave DS ordering (no barriers).
__device__ __forceinline__ int sladdr(int wid, int row, int byte) {
    return SLAB_BASE + (wid << 13) + (row << 8) +
           ((((byte >> 4) ^ row) & 15) << 4) + (byte & 15);
}

__global__ __launch_bounds__(THREADS, 2)   // 256-reg cap incl AGPR
void ar_gas_v10(const float* __restrict__ x,
                const float* __restrict__ last_mu,
                const float* __restrict__ last_sigma,
                const float* __restrict__ p_amu, const float* __restrict__ p_as,
                const float* __restrict__ p_bmu, const float* __restrict__ p_bs,
                const float* __restrict__ p_omu, const float* __restrict__ p_os,
                const float* __restrict__ p_nu,  const float* __restrict__ p_ns,
                const float* __restrict__ b1, const float* __restrict__ b2,
                const float* __restrict__ b3,
                const uint4* __restrict__ wf,
                float* __restrict__ out)
{
    extern __shared__ __align__(16) unsigned char L[];
    const int tid  = threadIdx.x;
    const int lane = tid & 63;
    const int wid  = tid >> 6;
    const int l15  = lane & 15;
    const int l4   = lane >> 4;
    const int blk  = blockIdx.x;

    // ---- stage the 96 KB fragment table into LDS (12 frags per wave) ----
    {
        const uint4* gsrc = wf + (wid * 12) * 64 + lane;   // per-lane source
        unsigned char* ldst = L + (wid * 12) * 1024;       // wave-uniform dest
        #pragma unroll
        for (int j = 0; j < 12; ++j)
            gload_lds16(gsrc + j * 64, ldst + j * 1024);
    }
    __syncthreads();   // drains vmcnt(0): frags resident; read-only after this

#define FRAG(f) (*(const uint4*)(&L[(f) * 1024 + lane * 16]))

    // wave-private global rows [gw, gw+32)
    const size_t gw = (size_t)blk * BMROWS + (size_t)wid * 32;
    const float* xp0 = x + (gw + l15) * 200;        // mt=0 A-rows
    const float* xp1 = x + (gw + 16 + l15) * 200;   // mt=1 A-rows

    // Unconditional 32B loads; tail lanes clamp to a valid addr — their
    // garbage values hit zero-padded W1 frag rows (k>=200) so contribute 0.
#define XLOAD(d0, d1, xp, kk)                                           \
    { int kb = (kk) * 32 + l4 * 8;                                      \
      kb = (kb + 8 <= 200) ? kb : 168;                                  \
      d0 = *(const float4*)((xp) + kb);                                 \
      d1 = *(const float4*)((xp) + kb + 4); }

    // ================= layer 1: h1 = relu(X @ W1 + b1) =================
    v4f acc[2][7];                          // 56 accumulator regs
    #pragma unroll
    for (int mt = 0; mt < 2; ++mt)
        #pragma unroll
        for (int nt = 0; nt < 7; ++nt) acc[mt][nt] = (v4f){0.f, 0.f, 0.f, 0.f};
    float bv[7];
    #pragma unroll
    for (int nt = 0; nt < 7; ++nt) {
        const int c = nt * 16 + l15;
        bv[nt] = (c < 100) ? b1[c] : 0.f;
    }

    float4 c0a, c0b, c1a, c1b;
    XLOAD(c0a, c0b, xp0, 0);
    XLOAD(c1a, c1b, xp1, 0);
    #pragma unroll
    for (int kc = 0; kc < 7; ++kc) {
        uint4 bu[7];                        // frags now from LDS (DS pipe)
        #pragma unroll
        for (int nt = 0; nt < 7; ++nt) bu[nt] = FRAG(W1F + nt * 7 + kc);
        const v8s af0 = mkfrag(c0a, c0b);
        const v8s af1 = mkfrag(c1a, c1b);
        if (kc < 6) {                       // prefetch next X chunk
            XLOAD(c0a, c0b, xp0, kc + 1);
            XLOAD(c1a, c1b, xp1, kc + 1);
        }
        #pragma unroll
        for (int nt = 0; nt < 7; ++nt) {
            const v8s bf = *(const v8s*)&bu[nt];
            acc[0][nt] = mfma16(af0, bf, acc[0][nt]);
            acc[1][nt] = mfma16(af1, bf, acc[1][nt]);
        }
    }
#undef XLOAD

    // epilogue -> slab (bf16), wave-private
    #pragma unroll
    for (int mt = 0; mt < 2; ++mt)
        #pragma unroll
        for (int nt = 0; nt < 7; ++nt) {
            #pragma unroll
            for (int r = 0; r < 4; ++r) {
                const int row = mt * 16 + l4 * 4 + r;
                const int c   = nt * 16 + l15;
                const float v = fmaxf(acc[mt][nt][r] + bv[nt], 0.f);
                *(unsigned short*)(&L[sladdr(wid, row, c * 2)]) = f2bf(v);
            }
        }
    // zero cols 112..127 (cols 100..111 are zero via zero-padded W1 frags)
    *(uint4*)(&L[sladdr(wid, lane >> 1, 224 + (lane & 1) * 16)]) =
        make_uint4(0, 0, 0, 0);

    // ================= layer 2: h2 = relu(h1 @ W2 + b2) =================
    v4f acc2[2][7];
    #pragma unroll
    for (int mt = 0; mt < 2; ++mt)
        #pragma unroll
        for (int nt = 0; nt < 7; ++nt) acc2[mt][nt] = (v4f){0.f, 0.f, 0.f, 0.f};
    float bv2[7];
    #pragma unroll
    for (int nt = 0; nt < 7; ++nt) {
        const int c = nt * 16 + l15;
        bv2[nt] = (c < 100) ? b2[c] : 0.f;
    }
    #pragma unroll
    for (int kc = 0; kc < 4; ++kc) {
        uint4 bu[7];
        #pragma unroll
        for (int nt = 0; nt < 7; ++nt) bu[nt] = FRAG(W2F + nt * 4 + kc);
        uint4 t0 = *(const uint4*)(&L[sladdr(wid, l15,      kc * 64 + l4 * 16)]);
        uint4 t1 = *(const uint4*)(&L[sladdr(wid, 16 + l15, kc * 64 + l4 * 16)]);
        const v8s af0 = *(v8s*)&t0;
        const v8s af1 = *(v8s*)&t1;
        #pragma unroll
        for (int nt = 0; nt < 7; ++nt) {
            const v8s bf = *(const v8s*)&bu[nt];
            acc2[0][nt] = mfma16(af0, bf, acc2[0][nt]);
            acc2[1][nt] = mfma16(af1, bf, acc2[1][nt]);
        }
    }
    // h2 overwrites h1 in-place (in-wave DS ordering); pad cols keep zeros
    #pragma unroll
    for (int mt = 0; mt < 2; ++mt)
        #pragma unroll
        for (int nt = 0; nt < 7; ++nt) {
            #pragma unroll
            for (int r = 0; r < 4; ++r) {
                const int row = mt * 16 + l4 * 4 + r;
                const int c   = nt * 16 + l15;
                const float v = fmaxf(acc2[mt][nt][r] + bv2[nt], 0.f);
                *(unsigned short*)(&L[sladdr(wid, row, c * 2)]) = f2bf(v);
            }
        }

    // ================= layer 3: DP = h2 @ W3 + b3 =================
    v4f acc3[2][4];
    #pragma unroll
    for (int mt = 0; mt < 2; ++mt)
        #pragma unroll
        for (int nt = 0; nt < 4; ++nt) acc3[mt][nt] = (v4f){0.f, 0.f, 0.f, 0.f};
    float bv3[4];
    #pragma unroll
    for (int nt = 0; nt < 4; ++nt) bv3[nt] = b3[nt * 16 + l15];

    #pragma unroll
    for (int kc = 0; kc < 4; ++kc) {
        uint4 bu[4];
        #pragma unroll
        for (int nt = 0; nt < 4; ++nt) bu[nt] = FRAG(W3F + nt * 4 + kc);
        uint4 t0 = *(const uint4*)(&L[sladdr(wid, l15,      kc * 64 + l4 * 16)]);
        uint4 t1 = *(const uint4*)(&L[sladdr(wid, 16 + l15, kc * 64 + l4 * 16)]);
        const v8s af0 = *(v8s*)&t0;
        const v8s af1 = *(v8s*)&t1;
        #pragma unroll
        for (int nt = 0; nt < 4; ++nt) {
            const v8s bf = *(const v8s*)&bu[nt];
            acc3[0][nt] = mfma16(af0, bf, acc3[0][nt]);
            acc3[1][nt] = mfma16(af1, bf, acc3[1][nt]);
        }
    }
#undef FRAG
    // DP (f32 [32 rows][64]) overwrites slab (h2 reads precede in program order)
    #pragma unroll
    for (int mt = 0; mt < 2; ++mt)
        #pragma unroll
        for (int nt = 0; nt < 4; ++nt) {
            #pragma unroll
            for (int r = 0; r < 4; ++r) {
                const int row = mt * 16 + l4 * 4 + r;
                const int c   = nt * 16 + l15;
                *(float*)(&L[sladdr(wid, row, c * 4)]) = acc3[mt][nt][r] + bv3[nt];
            }
        }

    // ====== Student-t GAS recurrence: per-wave, lane<32 owns one row ======
    if (lane < 32) {
        const size_t rg = gw + lane;
        float mu = last_mu[rg];
        float s2 = last_sigma[rg];
        const float anu = *p_nu,  ans = *p_ns;
        const float aMu = *p_amu, aSg = *p_as;
        const float bMu = *p_bmu, bSg = *p_bs;
        const float oMu = *p_omu, oSg = *p_os;
        const float w   = 1.f + __builtin_amdgcn_rcpf(anu);
        const float cmu = ans * aMu * w;
        const float cs  = ans * aSg * w;
        const float bs2 = bSg - ans * aSg;

#define GAS_STEP(Y, O)                                                  \
        {   const float e    = (Y) - mu;                                \
            const float nus2 = anu * s2;                                \
            const float den  = fmaf(e, e, nus2);                        \
            const float r0   = __builtin_amdgcn_rcpf(den);              \
            const float p    = e * nus2 * r0;                           \
            mu = fmaf(cmu, p, fmaf(bMu, mu, oMu));                      \
            s2 = fmaf(cs, e * p, fmaf(bs2, s2, oSg));                   \
            (O) = fmaf((Y), __builtin_amdgcn_sqrtf(s2), mu); }

        #pragma unroll
        for (int q = 0; q < 16; ++q) {
            float4 d = *(float4*)(&L[sladdr(wid, lane, q * 16)]);
            float o0, o1, o2, o3;
            GAS_STEP(d.x, o0); GAS_STEP(d.y, o1);
            GAS_STEP(d.z, o2); GAS_STEP(d.w, o3);
            *(float4*)(&L[sladdr(wid, lane, q * 16)]) = make_float4(o0, o1, o2, o3);
        }
#undef GAS_STEP
    }

    // ============ wave-wide coalesced float4 store (no barrier) ============
    #pragma unroll
    for (int i = 0; i < 8; ++i) {
        const int fi  = i * 64 + lane;           // 512 float4 = 32 rows x 64
        const int row = fi >> 4, q = fi & 15;
        float4 v = *(float4*)(&L[sladdr(wid, row, q * 16)]);
        ((float4*)out)[gw * 16 + fi] = v;
    }
}

extern "C" void kernel_launch(void* const* d_in, const int* in_sizes, int n_in,
                              void* d_out, int out_size, void* d_ws, size_t ws_size,
                              hipStream_t stream) {
    const float* x          = (const float*)d_in[0];
    const float* last_mu    = (const float*)d_in[1];
    const float* last_sigma = (const float*)d_in[2];
    const float* amu        = (const float*)d_in[3];
    const float* asig       = (const float*)d_in[4];
    const float* bmu        = (const float*)d_in[5];
    const float* bsig       = (const float*)d_in[6];
    const float* omu        = (const float*)d_in[7];
    const float* osig       = (const float*)d_in[8];
    const float* nu         = (const float*)d_in[9];
    const float* ns         = (const float*)d_in[10];
    const float* W1         = (const float*)d_in[11];
    const float* b1         = (const float*)d_in[12];
    const float* W2         = (const float*)d_in[13];
    const float* b2         = (const float*)d_in[14];
    const float* W3         = (const float*)d_in[15];
    const float* b3         = (const float*)d_in[16];
    float* out = (float*)d_out;

    uint4* wf = (uint4*)d_ws;   // 98,304 B fragment table (96 frags, 3 pad)
    prep_weights<<<96, 64, 0, stream>>>(W1, W2, W3, wf);

    hipFuncSetAttribute((const void*)ar_gas_v10,
                        hipFuncAttributeMaxDynamicSharedMemorySize, LDS_TOTAL);

    const int B = in_sizes[1];                 // 262144
    dim3 grid(B / BMROWS), block(THREADS);     // 1024 blocks x 512 threads
    ar_gas_v10<<<grid, block, LDS_TOTAL, stream>>>(
        x, last_mu, last_sigma,
        amu, asig, bmu, bsig, omu, osig, nu, ns,
        b1, b2, b3, wf, out);
}

// Round 11
// 87.076 us; speedup vs baseline: 1.9059x; 1.0521x over previous
//
#include <hip/hip_runtime.h>
#include <hip/hip_bf16.h>

typedef short v8s __attribute__((ext_vector_type(8)));
typedef float v4f __attribute__((ext_vector_type(4)));

#define THREADS 512      // 8 waves
#define BMROWS  128      // 16 rows per wave
// wf frag indices (93 frags in d_ws)
#define W1F     0        // 49 frags
#define W2F     49       // 28 frags
#define W3F     77       // 16 frags
// LDS: [W2: 28 frags @0..28K) [W1: 49 frags @28K..77K)
// slabs (8 x 4KB) overlay W1 region after the post-layer1 barrier;
// W3 (16 frags) overwrites W2 region after the post-layer2 barrier.
#define W1LDS   28       // W1 frag f lives at LDS slot 28+f
#define SLABB   28672
#define LDS_TOTAL 78848

__device__ __forceinline__ unsigned short f2bf(float f) {
    union { __hip_bfloat16 h; unsigned short u; } c;
    c.h = __float2bfloat16(f);
    return c.u;
}
__device__ __forceinline__ unsigned pk2(float a, float b) {
    return (unsigned)f2bf(a) | ((unsigned)f2bf(b) << 16);
}
__device__ __forceinline__ v4f mfma16(v8s a, v8s b, v4f c) {
    return __builtin_amdgcn_mfma_f32_16x16x32_bf16(a, b, c, 0, 0, 0);
}
__device__ __forceinline__ v8s mkfrag(float4 a, float4 b) {
    union { unsigned u[4]; v8s s; } t;
    t.u[0] = pk2(a.x, a.y); t.u[1] = pk2(a.z, a.w);
    t.u[2] = pk2(b.x, b.y); t.u[3] = pk2(b.z, b.w);
    return t.s;
}
__device__ __forceinline__ void gload_lds16(const void* g, void* l) {
    __builtin_amdgcn_global_load_lds(
        (const __attribute__((address_space(1))) void*)g,
        (__attribute__((address_space(3))) void*)l, 16, 0, 0);
}

// ---- prep: weights -> MFMA B-fragment layout (bf16, zero-padded) ----------
// frag(nt,kc): lane l holds B[k = kc*32+(l>>4)*8+j][n = nt*16+(l&15)], j=0..7
__global__ void prep_weights(const float* __restrict__ W1,
                             const float* __restrict__ W2,
                             const float* __restrict__ W3,
                             uint4* __restrict__ wf) {
    const int bid = blockIdx.x, l = threadIdx.x;
    const float* W; int K, N, KC, base, f;
    if (bid < 49)      { W = W1; K = 200; N = 100; KC = 7; base = W1F * 64; f = bid; }
    else if (bid < 77) { W = W2; K = 100; N = 100; KC = 4; base = W2F * 64; f = bid - 49; }
    else               { W = W3; K = 100; N = 64;  KC = 4; base = W3F * 64; f = bid - 77; }
    const int kc = f % KC;
    const int n  = (f / KC) * 16 + (l & 15);
    unsigned u[4];
    #pragma unroll
    for (int p = 0; p < 4; ++p) {
        const int k0 = kc * 32 + (l >> 4) * 8 + p * 2;
        const float a = (k0     < K && n < N) ? W[(size_t)k0 * N + n]       : 0.f;
        const float b = (k0 + 1 < K && n < N) ? W[(size_t)(k0 + 1) * N + n] : 0.f;
        u[p] = pk2(a, b);
    }
    wf[base + f * 64 + l] = make_uint4(u[0], u[1], u[2], u[3]);
}

// Per-wave 4 KiB slab overlaying the W1 region: [16 rows][256 B], XOR-16 swz.
__device__ __forceinline__ int sladdr(int wid, int row, int byte) {
    return SLABB + (wid << 12) + (row << 8) +
           ((((byte >> 4) ^ row) & 15) << 4) + (byte & 15);
}

__global__ __launch_bounds__(THREADS, 4)   // 128-reg cap -> 4 waves/SIMD
void ar_gas_v11(const float* __restrict__ x,
                const float* __restrict__ last_mu,
                const float* __restrict__ last_sigma,
                const float* __restrict__ p_amu, const float* __restrict__ p_as,
                const float* __restrict__ p_bmu, const float* __restrict__ p_bs,
                const float* __restrict__ p_omu, const float* __restrict__ p_os,
                const float* __restrict__ p_nu,  const float* __restrict__ p_ns,
                const float* __restrict__ b1, const float* __restrict__ b2,
                const float* __restrict__ b3,
                const uint4* __restrict__ wf,
                float* __restrict__ out)
{
    extern __shared__ __align__(16) unsigned char L[];
    const int tid  = threadIdx.x;
    const int lane = tid & 63;
    const int wid  = tid >> 6;
    const int l15  = lane & 15;
    const int l4   = lane >> 4;
    const int blk  = blockIdx.x;

    // wave-private global rows [gw, gw+16)
    const size_t gw = (size_t)blk * BMROWS + (size_t)wid * 16;
    const float* xp0 = x + (gw + l15) * 200;

    // hoisted state loads: consumed ~10K cyc later at GAS (free latency cover)
    const float mu_init = last_mu[gw + l15];
    const float s2_init = last_sigma[gw + l15];

#define XLOAD(d0, d1, kk)                                               \
    { int kb = (kk) * 32 + l4 * 8;                                      \
      kb = (kb + 8 <= 200) ? kb : 168;                                  \
      d0 = *(const float4*)(xp0 + kb);                                  \
      d1 = *(const float4*)(xp0 + kb + 4); }

    // X triple-buffer prologue (in flight during staging; barrier drains all)
    float4 xv[3][2];
    XLOAD(xv[0][0], xv[0][1], 0);
    XLOAD(xv[1][0], xv[1][1], 1);
    XLOAD(xv[2][0], xv[2][1], 2);

    float bv[7];
    #pragma unroll
    for (int nt = 0; nt < 7; ++nt) {
        const int c = nt * 16 + l15;
        bv[nt] = (c < 100) ? b1[c] : 0.f;
    }

    // ---- stage W2 (LDS slots 0..27) + W1 (slots 28..76) ----
    for (int s = wid; s < 77; s += 8) {
        const int src = (s < 28) ? (W2F + s - 0) : (W1F + s - 28);
        gload_lds16(wf + src * 64 + lane, L + s * 1024);
    }
    __syncthreads();   // barrier 1: frags resident (vmcnt(0) drain)

#define FRAG(slot) (*(const uint4*)(&L[(slot) * 1024 + lane * 16]))

    // ================= layer 1: h1 = relu(X @ W1 + b1) =================
    v4f acc[7];
    #pragma unroll
    for (int nt = 0; nt < 7; ++nt) acc[nt] = (v4f){0.f, 0.f, 0.f, 0.f};

    #pragma unroll
    for (int kc = 0; kc < 7; ++kc) {
        uint4 bu[7];
        #pragma unroll
        for (int nt = 0; nt < 7; ++nt) bu[nt] = FRAG(W1LDS + nt * 7 + kc);
        const v8s af = mkfrag(xv[kc % 3][0], xv[kc % 3][1]);
        if (kc < 4) XLOAD(xv[kc % 3][0], xv[kc % 3][1], kc + 3);  // 3-deep
        #pragma unroll
        for (int nt = 0; nt < 7; ++nt)
            acc[nt] = mfma16(af, *(const v8s*)&bu[nt], acc[nt]);
    }
#undef XLOAD

    __syncthreads();   // barrier 2: all waves done reading W1 -> slabs may overlay

    // epilogue -> slab (bf16 [16][128]), wave-private from here on
    #pragma unroll
    for (int nt = 0; nt < 7; ++nt) {
        #pragma unroll
        for (int r = 0; r < 4; ++r) {
            const int row = l4 * 4 + r;
            const int c   = nt * 16 + l15;
            const float v = fmaxf(acc[nt][r] + bv[nt], 0.f);
            *(unsigned short*)(&L[sladdr(wid, row, c * 2)]) = f2bf(v);
        }
    }
    // zero cols 112..127 (100..111 zero via zero-padded W1 frags)
    if (lane < 32)
        *(uint4*)(&L[sladdr(wid, lane >> 1, 224 + (lane & 1) * 16)]) =
            make_uint4(0, 0, 0, 0);

    // ================= layer 2: h2 = relu(h1 @ W2 + b2) =================
    float bv2[7];
    #pragma unroll
    for (int nt = 0; nt < 7; ++nt) {
        const int c = nt * 16 + l15;
        bv2[nt] = (c < 100) ? b2[c] : 0.f;
    }
    v4f acc2[7];
    #pragma unroll
    for (int nt = 0; nt < 7; ++nt) acc2[nt] = (v4f){0.f, 0.f, 0.f, 0.f};

    #pragma unroll
    for (int kc = 0; kc < 4; ++kc) {
        uint4 bu[7];
        #pragma unroll
        for (int nt = 0; nt < 7; ++nt) bu[nt] = FRAG(nt * 4 + kc);   // W2 slots
        uint4 t0 = *(const uint4*)(&L[sladdr(wid, l15, kc * 64 + l4 * 16)]);
        const v8s af = *(v8s*)&t0;
        #pragma unroll
        for (int nt = 0; nt < 7; ++nt)
            acc2[nt] = mfma16(af, *(const v8s*)&bu[nt], acc2[nt]);
    }

    __syncthreads();   // barrier 3: all waves done reading W2 region

    // stage W3 into the dead W2 region (slots 0..15); latency hidden by epilogue
    for (int s = wid; s < 16; s += 8)
        gload_lds16(wf + (W3F + s) * 64 + lane, L + s * 1024);

    // h2 -> slab (overlaps W3 staging); pad cols keep zeros
    #pragma unroll
    for (int nt = 0; nt < 7; ++nt) {
        #pragma unroll
        for (int r = 0; r < 4; ++r) {
            const int row = l4 * 4 + r;
            const int c   = nt * 16 + l15;
            const float v = fmaxf(acc2[nt][r] + bv2[nt], 0.f);
            *(unsigned short*)(&L[sladdr(wid, row, c * 2)]) = f2bf(v);
        }
    }

    __syncthreads();   // barrier 4: W3 resident (vmcnt drain) + h2 visible

    // ================= layer 3: DP = h2 @ W3 + b3 =================
    float bv3[4];
    #pragma unroll
    for (int nt = 0; nt < 4; ++nt) bv3[nt] = b3[nt * 16 + l15];
    v4f acc3[4];
    #pragma unroll
    for (int nt = 0; nt < 4; ++nt) acc3[nt] = (v4f){0.f, 0.f, 0.f, 0.f};

    #pragma unroll
    for (int kc = 0; kc < 4; ++kc) {
        uint4 bu[4];
        #pragma unroll
        for (int nt = 0; nt < 4; ++nt) bu[nt] = FRAG(nt * 4 + kc);   // W3 slots
        uint4 t0 = *(const uint4*)(&L[sladdr(wid, l15, kc * 64 + l4 * 16)]);
        const v8s af = *(v8s*)&t0;
        #pragma unroll
        for (int nt = 0; nt < 4; ++nt)
            acc3[nt] = mfma16(af, *(const v8s*)&bu[nt], acc3[nt]);
    }
#undef FRAG

    // DP (f32 [16][64]) overwrites slab (h2 reads precede in program order)
    #pragma unroll
    for (int nt = 0; nt < 4; ++nt) {
        #pragma unroll
        for (int r = 0; r < 4; ++r) {
            const int row = l4 * 4 + r;
            const int c   = nt * 16 + l15;
            *(float*)(&L[sladdr(wid, row, c * 4)]) = acc3[nt][r] + bv3[nt];
        }
    }

    // ====== Student-t GAS recurrence: per-wave, lane<16 owns one row ======
    if (lane < 16) {
        float mu = mu_init;
        float s2 = s2_init;
        const float anu = *p_nu,  ans = *p_ns;
        const float aMu = *p_amu, aSg = *p_as;
        const float bMu = *p_bmu, bSg = *p_bs;
        const float oMu = *p_omu, oSg = *p_os;
        const float w   = 1.f + __builtin_amdgcn_rcpf(anu);
        const float cmu = ans * aMu * w;
        const float cs  = ans * aSg * w;
        const float bs2 = bSg - ans * aSg;

#define GAS_STEP(Y, O)                                                  \
        {   const float e    = (Y) - mu;                                \
            const float nus2 = anu * s2;                                \
            const float den  = fmaf(e, e, nus2);                        \
            const float r0   = __builtin_amdgcn_rcpf(den);              \
            const float p    = e * nus2 * r0;                           \
            mu = fmaf(cmu, p, fmaf(bMu, mu, oMu));                      \
            s2 = fmaf(cs, e * p, fmaf(bs2, s2, oSg));                   \
            (O) = fmaf((Y), __builtin_amdgcn_sqrtf(s2), mu); }

        #pragma unroll
        for (int q = 0; q < 16; ++q) {
            float4 d = *(float4*)(&L[sladdr(wid, lane, q * 16)]);
            float o0, o1, o2, o3;
            GAS_STEP(d.x, o0); GAS_STEP(d.y, o1);
            GAS_STEP(d.z, o2); GAS_STEP(d.w, o3);
            *(float4*)(&L[sladdr(wid, lane, q * 16)]) = make_float4(o0, o1, o2, o3);
        }
#undef GAS_STEP
    }

    // ============ wave-wide coalesced float4 store (no barrier) ============
    #pragma unroll
    for (int i = 0; i < 4; ++i) {
        const int fi  = i * 64 + lane;           // 256 float4 = 16 rows x 16
        const int row = fi >> 4, q = fi & 15;
        float4 v = *(float4*)(&L[sladdr(wid, row, q * 16)]);
        ((float4*)out)[gw * 16 + fi] = v;
    }
}

extern "C" void kernel_launch(void* const* d_in, const int* in_sizes, int n_in,
                              void* d_out, int out_size, void* d_ws, size_t ws_size,
                              hipStream_t stream) {
    const float* x          = (const float*)d_in[0];
    const float* last_mu    = (const float*)d_in[1];
    const float* last_sigma = (const float*)d_in[2];
    const float* amu        = (const float*)d_in[3];
    const float* asig       = (const float*)d_in[4];
    const float* bmu        = (const float*)d_in[5];
    const float* bsig       = (const float*)d_in[6];
    const float* omu        = (const float*)d_in[7];
    const float* osig       = (const float*)d_in[8];
    const float* nu         = (const float*)d_in[9];
    const float* ns         = (const float*)d_in[10];
    const float* W1         = (const float*)d_in[11];
    const float* b1         = (const float*)d_in[12];
    const float* W2         = (const float*)d_in[13];
    const float* b2         = (const float*)d_in[14];
    const float* W3         = (const float*)d_in[15];
    const float* b3         = (const float*)d_in[16];
    float* out = (float*)d_out;

    uint4* wf = (uint4*)d_ws;   // 95,232 B fragment table (93 frags)
    prep_weights<<<93, 64, 0, stream>>>(W1, W2, W3, wf);

    hipFuncSetAttribute((const void*)ar_gas_v11,
                        hipFuncAttributeMaxDynamicSharedMemorySize, LDS_TOTAL);

    const int B = in_sizes[1];                 // 262144
    dim3 grid(B / BMROWS), block(THREADS);     // 2048 blocks x 512 threads
    ar_gas_v11<<<grid, block, LDS_TOTAL, stream>>>(
        x, last_mu, last_sigma,
        amu, asig, bmu, bsig, omu, osig, nu, ns,
        b1, b2, b3, wf, out);
}